// Round 9
// baseline (89.982 us; speedup 1.0000x reference)
//
#include <hip/hip_runtime.h>
#include <math.h>

#define NBATCH 128
#define S 7
#define CH 30
#define N 12544              // 128*7*7*2
#define PERB 98              // boxes per batch (49 cells x 2)
#define CLEN 784             // boxes per column chunk (N/NCHUNK)
#define NCHUNK 16
#define THRNMS 0.3

// f32 sigmoid cascade, bit-matching the numpy f32 reference (validated r3-r8):
//   e = expf(-x) (f64 exp rounded once = correctly-rounded f32 exp)
//   s = 1.0f / (1.0f + e)
__device__ __forceinline__ float sigf(float x) {
    float e = (float)exp(-(double)x);
    return 1.0f / (1.0f + e);
}

// raw objectness logit of box i
__device__ __forceinline__ float confraw(const float* __restrict__ p, int i) {
    return p[(i >> 1) * CH + 8 + (i & 1)];
}

// ========== K1: rank-from-scratch (no decode dependency) ==========
// grid (49, 16). Block (rb, ch): recompute column chunk ch's valid keys into
// LDS, recompute 256 row keys, emit collision-free partial counts:
//   valid row i:   vpart[ch][i] = #{valid j in chunk : Kj > Ki}   (global rank)
//   invalid row i: vpart[ch][i] = #{valid j in chunk : j < i}     (V_exc term)
// K = (f32_key_bits << 32) | idx  =>  K-desc == score-desc, tie idx-desc.
// valid <=> sigf(craw) > 0.5f; prefilter craw > 0 is exact (craw<=0 => <=0.5).
__global__ __launch_bounds__(256) void k_rank(
    const float* __restrict__ p,
    unsigned int* __restrict__ vpart)     // [NCHUNK][N], every slot written once
{
    __shared__ unsigned long long lk[CLEN];
    __shared__ unsigned int cnt_sh;
    const int tid = threadIdx.x;
    const int rb = blockIdx.x, ch = blockIdx.y;

    if (tid == 0) cnt_sh = 0u;
    __syncthreads();

    // column side: compact valid keys of chunk ch (order irrelevant for counts)
    for (int u = tid; u < CLEN; u += 256) {
        int jg = ch * CLEN + u;
        float craw = confraw(p, jg);
        if (craw > 0.0f) {
            float sc = sigf(craw);
            if (sc > 0.5f) {
                unsigned int m = atomicAdd(&cnt_sh, 1u);
                lk[m] = ((unsigned long long)__float_as_uint(sc) << 32)
                        | (unsigned long long)(unsigned int)jg;
            }
        }
    }
    __syncthreads();
    const unsigned int len = cnt_sh;

    // row side
    const int i = rb * 256 + tid;
    float crawi = confraw(p, i);
    bool validi = false;
    unsigned long long Ki = 0ull;
    if (crawi > 0.0f) {
        float sc = sigf(crawi);
        if (sc > 0.5f) {
            validi = true;
            Ki = ((unsigned long long)__float_as_uint(sc) << 32)
                 | (unsigned long long)(unsigned int)i;
        }
    }

    const unsigned int ui = (unsigned int)i;
    unsigned int cnt = 0;
    for (unsigned int u = 0; u < len; ++u) {
        unsigned long long K = lk[u];
        unsigned int c1 = (K > Ki) ? 1u : 0u;                 // valid-row count
        unsigned int c2 = ((unsigned int)K < ui) ? 1u : 0u;   // invalid-row count
        cnt += validi ? c1 : c2;
    }
    vpart[ch * N + i] = cnt;     // plain store, exactly-once coverage
}

// ========== K2: finish — full decode of own 98 boxes + NMS + all writes ==========
// Block b owns boxes [b*98, (b+1)*98) == cells [b*49, (b+1)*49).
__global__ __launch_bounds__(256) void k_finish(
    const float* __restrict__ p,
    const unsigned int* __restrict__ vpart,
    float* __restrict__ out)
{
    const int b   = blockIdx.x;
    const int tid = threadIdx.x;
    __shared__ int   lab49[49];            // per-cell label (shared by both boxes)
    __shared__ float bxa[PERB][4];         // own boxes, local order
    __shared__ float sca[PERB];
    __shared__ unsigned long long Ka[PERB];// 0 for invalid
    __shared__ unsigned int posa[PERB];    // final output row
    __shared__ int   srk[PERB];            // local box -> sorted member slot
    __shared__ float sbx[PERB][4];         // members sorted by K desc
    __shared__ int   slb[PERB], sup[PERB];
    __shared__ unsigned int kb_sh;

    if (tid == 0) kb_sh = 0u;

    // per-cell 20-class argmax, split across thread pairs (validated r6 pattern)
    if (tid < PERB) {
        int c = tid >> 1, half = tid & 1;
        const float* pc = p + (b * 49 + c) * CH;
        int cbase = 10 + half * 10;
        float best = sigf(pc[cbase]); int lab = half * 10;
        #pragma unroll
        for (int q = 1; q < 10; ++q) {
            float v = sigf(pc[cbase + q]);
            if (v > best) { best = v; lab = half * 10 + q; }
        }
        float obest = __shfl_xor(best, 1);
        int   olab  = __shfl_xor(lab, 1);
        float bestA = half ? obest : best;  int labA = half ? olab : lab;  // cls 0-9
        float bestB = half ? best  : obest; int labB = half ? lab  : olab; // cls 10-19
        if (half == 0) lab49[c] = (bestB > bestA ? labB : labA) + 1;  // first max wins
    }

    // own-box decode + position (sum of 16 rank partials)
    if (tid < PERB) {
        int i = b * PERB + tid;
        int j = tid & 1, c = tid >> 1;
        const float* pc = p + (b * 49 + c) * CH;
        float tx = pc[j*4+0], ty = pc[j*4+1], tw = pc[j*4+2], th = pc[j*4+3];
        float craw = pc[8 + j];

        float sx = sigf(tx), sy = sigf(ty);
        int xg = c % S, yg = c / S;       // b*49 divisible by 49 => local forms exact
        float cx = (sx + (float)xg) / 7.0f;
        float cy = (sy + (float)yg) / 7.0f;
        float hw = tw / 2.0f, hh = th / 2.0f;
        bxa[tid][0] = cx - hw; bxa[tid][1] = cy - hh;
        bxa[tid][2] = cx + hw; bxa[tid][3] = cy + hh;

        float sc = sigf(craw);
        sca[tid] = sc;
        bool valid = sc > 0.5f;
        Ka[tid] = valid ? (((unsigned long long)__float_as_uint(sc) << 32)
                           | (unsigned long long)(unsigned int)i)
                        : 0ull;

        unsigned int acc = 0;
        #pragma unroll
        for (int chn = 0; chn < NCHUNK; ++chn) acc += vpart[chn * N + i];
        posa[tid] = valid ? acc : (unsigned int)(N - 1 - i) + acc;  // proven forms
        if (valid) atomicAdd(&kb_sh, 1u);
    }
    __syncthreads();
    const int kb = (int)kb_sh;            // <= 98 structurally

    // member sort: valid own boxes by K desc (== within-batch global order)
    if (tid < PERB && Ka[tid] != 0ull) {
        unsigned long long Kt = Ka[tid];
        int rk = 0;
        for (int u = 0; u < PERB; ++u) rk += (Ka[u] > Kt) ? 1 : 0;  // invalid=0 never counts
        srk[tid] = rk;
        sbx[rk][0] = bxa[tid][0]; sbx[rk][1] = bxa[tid][1];
        sbx[rk][2] = bxa[tid][2]; sbx[rk][3] = bxa[tid][3];
        slb[rk] = lab49[tid >> 1];
        sup[rk] = 0;
    }
    __syncthreads();

    // greedy NMS (proven r6-r8 loop)
    for (int i = 0; i < kb; ++i) {
        __syncthreads();
        if (sup[i]) continue;             // uniform broadcast read
        float li = sbx[i][0], ti = sbx[i][1], ri = sbx[i][2], bi = sbx[i][3];
        float areai = (ri - li) * (bi - ti);
        int labi = slb[i];
        int jj = tid;
        if (jj > i && jj < kb && slb[jj] == labi) {
            float lj = sbx[jj][0], tj = sbx[jj][1], rj = sbx[jj][2], bj = sbx[jj][3];
            float lt0 = fmaxf(li, lj), lt1 = fmaxf(ti, tj);
            float rb0 = fminf(ri, rj), rb1 = fminf(bi, bj);
            float w = rb0 - lt0; if (w < 0.0f) w = 0.0f;
            float h = rb1 - lt1; if (h < 0.0f) h = 0.0f;
            float inter = w * h;
            float areaj = (rj - lj) * (bj - tj);
            float uni = areai + areaj - inter;
            double iou = (double)inter / fmax((double)uni, 1e-9);
            if (iou > THRNMS) sup[jj] = 1;
        }
    }
    __syncthreads();

    // write all 98 complete output rows
    if (tid < PERB) {
        unsigned int pos = posa[tid];
        bool valid = Ka[tid] != 0ull;
        out[pos] = (float)b;
        ((float4*)(out + N))[pos] =
            make_float4(bxa[tid][0], bxa[tid][1], bxa[tid][2], bxa[tid][3]);
        out[5*N + pos] = (float)lab49[tid >> 1];
        out[6*N + pos] = sca[tid];
        out[7*N + pos] = (valid && !sup[srk[tid]]) ? 1.0f : 0.0f;
    }
}

extern "C" void kernel_launch(void* const* d_in, const int* in_sizes, int n_in,
                              void* d_out, int out_size, void* d_ws, size_t ws_size,
                              hipStream_t stream)
{
    const float* p = (const float*)d_in[0];
    float* out = (float*)d_out;
    unsigned int* vpart = (unsigned int*)d_ws;     // NCHUNK*N*4 = 784 KiB

    k_rank  <<<dim3(49, NCHUNK), dim3(256), 0, stream>>>(p, vpart);
    k_finish<<<dim3(NBATCH),     dim3(256), 0, stream>>>(p, vpart, out);
}

// Round 10
// 89.314 us; speedup vs baseline: 1.0075x; 1.0075x over previous
//
#include <hip/hip_runtime.h>
#include <math.h>

#define NBATCH 128
#define S 7
#define CH 30
#define N 12544              // 128*7*7*2
#define PERB 98              // boxes per batch (49 cells x 2)
#define NCH 16               // rank column chunks
#define CLEN 784             // N/NCH keys per chunk
#define THRNMS 0.3

// f32 sigmoid cascade, bit-matching the numpy f32 reference (validated r3-r9):
//   e = expf(-x) (f64 exp rounded once = correctly-rounded f32 exp)
//   s = 1.0f / (1.0f + e)
__device__ __forceinline__ float sigf(float x) {
    float e = (float)exp(-(double)x);
    return 1.0f / (1.0f + e);
}

// ========== K1: decode — uniform sort keys + box/score/label records ==========
// K[i] = valid ? (f32_score_bits << 32)|i : i.
// Full-domain comparator #{Kj > Ki} yields the reference position for BOTH
// valid rows (score desc, idx desc ties) and invalid rows (= nv + #{invalid
// j > i} = (N-1-i)+V_inc(i), the proven closed form) — no compaction needed.
__global__ __launch_bounds__(256) void k_decode(
    const float* __restrict__ p,
    unsigned long long* __restrict__ K,
    float4* __restrict__ box4,
    float* __restrict__ score,
    int* __restrict__ meta)
{
    int i    = blockIdx.x * 256 + threadIdx.x;   // exactly N threads
    int j    = i & 1;
    int cell = i >> 1;
    int x = cell % S, y = (cell / S) % S;
    const float* pc = p + cell * CH;

    float tx = pc[j*4+0], ty = pc[j*4+1], tw = pc[j*4+2], th = pc[j*4+3];
    float craw = pc[8 + j];

    // 20-class argmax split across the even/odd lane pair (same cell);
    // merge keeps first-occurrence semantics (validated r6-r9).
    int cbase = 10 + j * 10;
    float best = sigf(pc[cbase]); int lab = j * 10;
    #pragma unroll
    for (int c = 1; c < 10; ++c) {
        float v = sigf(pc[cbase + c]);
        if (v > best) { best = v; lab = j * 10 + c; }
    }
    float obest = __shfl_xor(best, 1);
    int   olab  = __shfl_xor(lab, 1);
    float bestA = j ? obest : best;  int labA = j ? olab : lab;   // classes 0-9
    float bestB = j ? best  : obest; int labB = j ? lab  : olab;  // classes 10-19
    int label = (bestB > bestA ? labB : labA) + 1;   // strict >: first max wins

    // f32 box geometry in numpy op order
    float sx = sigf(tx), sy = sigf(ty);
    float cx = (sx + (float)x) / 7.0f;
    float cy = (sy + (float)y) / 7.0f;
    float hw = tw / 2.0f, hh = th / 2.0f;
    float l = cx - hw, t = cy - hh, r = cx + hw, bt = cy + hh;

    float sc = sigf(craw);
    bool valid = sc > 0.5f;

    K[i] = valid ? (((unsigned long long)__float_as_uint(sc) << 32)
                    | (unsigned long long)(unsigned int)i)
                 : (unsigned long long)(unsigned int)i;
    box4[i]  = make_float4(l, t, r, bt);
    score[i] = sc;
    meta[i]  = label;
}

// ========== K2: full-domain rank, collision-free partial counts ==========
// grid (49, 16). Block (rb, ch): chunk ch's 784 keys -> LDS, each row thread
// counts Kj > Ki. Plain store vpart[ch][i] (written exactly once: no init,
// no atomics). All bounds compile-time constant.
__global__ __launch_bounds__(256) void k_rank(
    const unsigned long long* __restrict__ K,
    unsigned int* __restrict__ vpart)     // [NCH][N]
{
    __shared__ unsigned long long lk[CLEN];
    const int tid = threadIdx.x;
    const unsigned int base = blockIdx.y * CLEN;

    for (int u = tid; u < CLEN; u += 256) lk[u] = K[base + u];
    __syncthreads();

    const unsigned int row = blockIdx.x * 256 + tid;
    const unsigned long long Ki = K[row];
    unsigned int cnt = 0;
    #pragma unroll 8
    for (int u = 0; u < CLEN; ++u)
        cnt += (lk[u] > Ki) ? 1u : 0u;    // desc key, tie desc idx
    vpart[blockIdx.y * N + row] = cnt;
}

// ========== K3: finish — positions + member sort + NMS + all writes ==========
// One block per batch; boxes [b*98,(b+1)*98) are contiguous. pos = sum of 16
// partials (uniform for valid AND invalid). Within-batch NMS order = K desc.
__global__ __launch_bounds__(128) void k_finish(
    const unsigned long long* __restrict__ K,
    const float4* __restrict__ box4,
    const float* __restrict__ score,
    const int* __restrict__ meta,
    const unsigned int* __restrict__ vpart,
    float* __restrict__ out)
{
    const int b = blockIdx.x, tid = threadIdx.x;
    __shared__ unsigned long long Ka[PERB];
    __shared__ float bxa[PERB][4];
    __shared__ float sca[PERB];
    __shared__ int   laba[PERB];
    __shared__ unsigned int posa[PERB];
    __shared__ int   srk[PERB];
    __shared__ float sbx[PERB][4];        // members sorted by K desc
    __shared__ int   slb[PERB], sup[PERB];
    __shared__ unsigned int kb_sh;

    if (tid == 0) kb_sh = 0u;
    __syncthreads();                      // init strictly before the atomics

    if (tid < PERB) {
        int i = b * PERB + tid;
        unsigned long long Kt = K[i];
        Ka[tid] = Kt;
        float4 v = box4[i];
        bxa[tid][0] = v.x; bxa[tid][1] = v.y; bxa[tid][2] = v.z; bxa[tid][3] = v.w;
        sca[tid]  = score[i];
        laba[tid] = meta[i];
        unsigned int acc = 0;
        #pragma unroll
        for (int ch = 0; ch < NCH; ++ch) acc += vpart[ch * N + i];
        posa[tid] = acc;                  // reference position, valid or not
        if (Kt >> 32) atomicAdd(&kb_sh, 1u);
    }
    __syncthreads();
    const int kb = (int)kb_sh;            // <= 98 structurally

    if (tid < PERB && (Ka[tid] >> 32)) {  // valid: rank-sort by K desc
        unsigned long long Kt = Ka[tid];
        int rk = 0;
        for (int u = 0; u < PERB; ++u)
            rk += (Ka[u] > Kt) ? 1 : 0;   // invalid Ka < 2^32 never counts
        srk[tid] = rk;
        sbx[rk][0] = bxa[tid][0]; sbx[rk][1] = bxa[tid][1];
        sbx[rk][2] = bxa[tid][2]; sbx[rk][3] = bxa[tid][3];
        slb[rk] = laba[tid];
        sup[rk] = 0;
    }
    __syncthreads();

    // greedy NMS (proven r6-r9 loop)
    for (int i = 0; i < kb; ++i) {
        __syncthreads();
        if (sup[i]) continue;             // uniform broadcast read
        float li = sbx[i][0], ti = sbx[i][1], ri = sbx[i][2], bi = sbx[i][3];
        float areai = (ri - li) * (bi - ti);
        int labi = slb[i];
        int jj = tid;
        if (jj > i && jj < kb && slb[jj] == labi) {
            float lj = sbx[jj][0], tj = sbx[jj][1], rj = sbx[jj][2], bj = sbx[jj][3];
            float lt0 = fmaxf(li, lj), lt1 = fmaxf(ti, tj);
            float rb0 = fminf(ri, rj), rb1 = fminf(bi, bj);
            float w = rb0 - lt0; if (w < 0.0f) w = 0.0f;
            float h = rb1 - lt1; if (h < 0.0f) h = 0.0f;
            float inter = w * h;
            float areaj = (rj - lj) * (bj - tj);
            float uni = areai + areaj - inter;
            double iou = (double)inter / fmax((double)uni, 1e-9);
            if (iou > THRNMS) sup[jj] = 1;
        }
    }
    __syncthreads();

    if (tid < PERB) {                     // write complete output rows
        unsigned int pos = posa[tid];
        bool valid = (Ka[tid] >> 32) != 0ull;
        out[pos] = (float)b;
        ((float4*)(out + N))[pos] =
            make_float4(bxa[tid][0], bxa[tid][1], bxa[tid][2], bxa[tid][3]);
        out[5*N + pos] = (float)laba[tid];
        out[6*N + pos] = sca[tid];
        out[7*N + pos] = (valid && !sup[srk[tid]]) ? 1.0f : 0.0f;
    }
}

extern "C" void kernel_launch(void* const* d_in, const int* in_sizes, int n_in,
                              void* d_out, int out_size, void* d_ws, size_t ws_size,
                              hipStream_t stream)
{
    const float* p = (const float*)d_in[0];
    float* out = (float*)d_out;

    char* w = (char*)d_ws;
    float4* box4        = (float4*)w;                     w += (size_t)N * 16;
    unsigned long long* K = (unsigned long long*)w;       w += (size_t)N * 8;
    float* score        = (float*)w;                      w += (size_t)N * 4;
    int* meta           = (int*)w;                        w += (size_t)N * 4;
    unsigned int* vpart = (unsigned int*)w;               w += (size_t)NCH * N * 4;

    k_decode<<<dim3(N / 256),   dim3(256), 0, stream>>>(p, K, box4, score, meta);
    k_rank  <<<dim3(49, NCH),   dim3(256), 0, stream>>>(K, vpart);
    k_finish<<<dim3(NBATCH),    dim3(128), 0, stream>>>(K, box4, score, meta, vpart, out);
}